// Round 16
// baseline (103.006 us; speedup 1.0000x reference)
//
#include <hip/hip_runtime.h>
#include <hip/hip_bf16.h>

// Bahdanau additive attention, MI355X.  B=8, TE=TD=256, HE=HD=512.
// d_in (f32): enc [B,TE,H], dec [B,TD,H], W_a [H,H], U_a [H,H], V_a [H,1]
// d_out (f32): c [B,TD,H] | e [B,TD,TE]
//
// Math: tanh(x) = 1 - 2/(1+e^{2x}).  score = Sv - 2*A,
// A[d,t] = sum_k Va[k]/(1 + EW[t,k]*EU[d,k]),  EW = exp2(clamp(2log2e*enc@Wa,±15)).
// Sv const over t -> dropped; softmax over min(A), -2 folded into exp2 const.
// R16 = R15 with the k-coverage bug fixed (R15 covered only 256/512 k:
//   ewbase used kh*32*1024 and 8 chunks; correct is kh*64*1024 and 16 chunks,
//   eub/vab offset kh*256). Scalar-pipe score: u,v via wave-uniform s_load,
//   ew VGPR-resident. Inner loop: pure VALU + rcp; 0 ds_read, 0 per-elem VMEM.
// ws (10MB): EW4 4M | EU 4M | encT 2M

#define BB  8
#define TEE 256
#define TDD 256
#define HH  512
#define C2LOG2E 2.8853900817779268f   // 2*log2(e)

typedef __attribute__((ext_vector_type(8))) short  short8;
typedef __attribute__((ext_vector_type(4))) float  floatx4;

__device__ __forceinline__ unsigned short f2bf(float f) {
  __hip_bfloat16 h = __float2bfloat16(f);      // RNE
  return __builtin_bit_cast(unsigned short, h);
}

// ---------------- K1: proj -> EW4 (transposed) / EU (row-major) + encT ----------------
// grid 768 x 256thr: blocks 0..255 EW4, 256..511 EU, 512..767 encT.
__global__ __launch_bounds__(256) void prep_proj(
    const float* __restrict__ enc, const float* __restrict__ dec,
    const float* __restrict__ Wa,  const float* __restrict__ Ua,
    float* __restrict__ EW4, float* __restrict__ EU,
    unsigned short* __restrict__ encT)
{
  __shared__ float tile[64][68];
  const int bid = blockIdx.x;
  const int tid = threadIdx.x;

  if (bid < 512) {
    const int side = bid >> 8;               // 0 = EW, 1 = EU
    const int lb = bid & 255;
    const float* X = side ? dec : enc;
    const float* W = side ? Ua  : Wa;
    const int lane = tid & 63, w = tid >> 6;
    const int m0b = (lb >> 3) * 64;          // block m-base (64 rows)
    const int m0 = m0b + w * 16;             // wave's 16 rows
    const int n0 = (lb & 7) * 64;
    const int r15 = lane & 15, g = lane >> 4;

    floatx4 acc[4] = {{0.f,0.f,0.f,0.f},{0.f,0.f,0.f,0.f},
                      {0.f,0.f,0.f,0.f},{0.f,0.f,0.f,0.f}};
    const float* ap = X + (size_t)(m0 + r15) * HH + g * 8;

    for (int k0 = 0; k0 < HH; k0 += 32) {
      float4 a0 = *(const float4*)(ap + k0);
      float4 a1 = *(const float4*)(ap + k0 + 4);
      short8 a;                               // 2log2e folded into A side
      a[0]=(short)f2bf(a0.x*C2LOG2E); a[1]=(short)f2bf(a0.y*C2LOG2E);
      a[2]=(short)f2bf(a0.z*C2LOG2E); a[3]=(short)f2bf(a0.w*C2LOG2E);
      a[4]=(short)f2bf(a1.x*C2LOG2E); a[5]=(short)f2bf(a1.y*C2LOG2E);
      a[6]=(short)f2bf(a1.z*C2LOG2E); a[7]=(short)f2bf(a1.w*C2LOG2E);
      const float* wrow = W + (size_t)(k0 + g * 8) * HH + n0 + r15;
      #pragma unroll
      for (int nt = 0; nt < 4; ++nt) {
        short8 bv;
        #pragma unroll
        for (int j = 0; j < 8; ++j) bv[j] = (short)f2bf(wrow[(size_t)j * HH + nt * 16]);
        acc[nt] = __builtin_amdgcn_mfma_f32_16x16x32_bf16(a, bv, acc[nt], 0, 0, 0);
      }
    }
    // D: col = lane&15, row = (lane>>4)*4 + reg  [m89-verified]
    if (side == 1) {
      // EU: direct row-major [d][k] write
      #pragma unroll
      for (int nt = 0; nt < 4; ++nt) {
        float* yp = EU + (size_t)(m0 + g * 4) * HH + n0 + nt * 16 + r15;
        #pragma unroll
        for (int r = 0; r < 4; ++r) {
          float v = fminf(fmaxf(acc[nt][r], -15.f), 15.f);
          yp[(size_t)r * HH] = __builtin_amdgcn_exp2f(v);
        }
      }
    } else {
      // EW: exp2 -> LDS tile -> transposed coalesced write to EW4
      #pragma unroll
      for (int nt = 0; nt < 4; ++nt) {
        #pragma unroll
        for (int r = 0; r < 4; ++r) {
          float v = fminf(fmaxf(acc[nt][r], -15.f), 15.f);
          tile[w * 16 + g * 4 + r][nt * 16 + r15] = __builtin_amdgcn_exp2f(v);
        }
      }
      __syncthreads();
      // EW4 elem (k,t): b*131072 + (k>>2)*1024 + t*4 + (k&3)
      #pragma unroll
      for (int i = 0; i < 4; ++i) {
        const int cell = i * 256 + tid;        // 1024 cells = 64 t x 16 k4
        const int tl  = cell & 63;
        const int k4l = cell >> 6;
        const int m   = m0b + tl;
        const int b   = m >> 8, t = m & 255;
        const int k4  = (n0 >> 2) + k4l;
        float4 val = *(const float4*)&tile[tl][k4l * 4];
        *(float4*)(EW4 + (size_t)b * 131072 + (size_t)k4 * 1024 + t * 4) = val;
      }
    }
  } else {
    // encT[b][h][t] = bf16(enc[b][t][h]); 256 blocks: 8 b x 8 h-tiles x 4 t-tiles
    const int idx = bid - 512;
    const int b  = idx >> 5;
    const int h0 = ((idx >> 2) & 7) * 64;
    const int t0 = (idx & 3) * 64;
    const int c = tid & 63, r4 = tid >> 6;
    #pragma unroll
    for (int i = 0; i < 16; ++i) {
      int tr = i * 4 + r4;
      tile[tr][c] = enc[((size_t)b * TEE + t0 + tr) * HH + h0 + c];
    }
    __syncthreads();
    #pragma unroll
    for (int i = 0; i < 16; ++i) {
      int hr = i * 4 + r4;
      encT[((size_t)b * HH + h0 + hr) * TEE + t0 + c] = f2bf(tile[c][hr]);
    }
  }
}

// ---------------- K2: scalar-pipe score + softmax + e + ctx MFMA ----------------
// grid 256 = 8 b x 32 d-stripes of 8; block 512 thr = 8 waves.
// wave wu: kh = wu>>2 (k-half, 256 k), tq = wu&3 (t-quarter); lane t = tq*64+lane.
// u/v via s_load (wave-uniform), ew in VGPRs (16-k chunks x 16). acc[8] over d.
__global__ __launch_bounds__(512, 2) void fused(
    const float* __restrict__ EW4, const float* __restrict__ EU,
    const float* __restrict__ Va, const unsigned short* __restrict__ encT,
    float* __restrict__ c_out, float* __restrict__ e_out)
{
  __shared__ float As[8][260];             // 8.3 KB
  __shared__ unsigned short pe[8][264];    // 4.2 KB

  const int bid = blockIdx.x;
  const int b  = bid >> 5;
  const int d0 = (bid & 31) * 8;
  const int tid = threadIdx.x;
  const int lane = tid & 63;
  const int wu = __builtin_amdgcn_readfirstlane(tid >> 6);  // scalar wave id 0..7
  const int kh = wu >> 2;                  // scalar k-half (256 k each)
  const int tq = wu & 3;                   // scalar t-quarter
  const int t  = tq * 64 + lane;

  // ---- score: pure-VALU 4-way rcp tree; u,v scalar; ew VGPR-resident
  float acc[8] = {};
  // EW4 elem (k,t): b*131072 + (k>>2)*1024 + t*4 + (k&3); k = kh*256 + c*16 + q*4 + j
  const float* ewbase = EW4 + (size_t)b * 131072 + (size_t)(kh * 64) * 1024 + t * 4;
  const float* eub = EU + ((size_t)(b * TDD) + d0) * HH + kh * 256;  // scalar base
  const float* vab = Va + kh * 256;                                   // scalar base

#define TREE(EW_, UP_, VP_, AC_) { \
    float A1 = fmaf(EW_.x, (UP_)[0], 1.0f); \
    float B1 = fmaf(EW_.y, (UP_)[1], 1.0f); \
    float C1 = fmaf(EW_.z, (UP_)[2], 1.0f); \
    float D1 = fmaf(EW_.w, (UP_)[3], 1.0f); \
    float dab = A1 * B1, dcd = C1 * D1; \
    float nab = fmaf((VP_)[0], B1, (VP_)[1] * A1); \
    float ncd = fmaf((VP_)[2], D1, (VP_)[3] * C1); \
    float den = dab * dcd; \
    float num = fmaf(nab, dcd, ncd * dab); \
    AC_ = fmaf(num, __builtin_amdgcn_rcpf(den), AC_); }

  float4 ew0 = *(const float4*)(ewbase);
  float4 ew1 = *(const float4*)(ewbase + 1024);
  float4 ew2 = *(const float4*)(ewbase + 2048);
  float4 ew3 = *(const float4*)(ewbase + 3072);

  for (int c = 0; c < 16; ++c) {           // 16 chunks of 16 k = 256 k
    float4 n0, n1, n2, n3;
    if (c + 1 < 16) {                      // depth-1 prefetch (covers ~900 VALU cy)
      const float* p = ewbase + (size_t)(c + 1) * 4096;
      n0 = *(const float4*)(p);
      n1 = *(const float4*)(p + 1024);
      n2 = *(const float4*)(p + 2048);
      n3 = *(const float4*)(p + 3072);
    }
    const float* vp = vab + c * 16;        // scalar
    #pragma unroll 2
    for (int d = 0; d < 8; ++d) {
      const float* up = eub + (size_t)d * HH + c * 16;   // scalar row
      TREE(ew0, up,      vp,      acc[d])
      TREE(ew1, up + 4,  vp + 4,  acc[d])
      TREE(ew2, up + 8,  vp + 8,  acc[d])
      TREE(ew3, up + 12, vp + 12, acc[d])
    }
    ew0 = n0; ew1 = n1; ew2 = n2; ew3 = n3;
  }
#undef TREE

  // combine k-halves in LDS (kh is scalar -> wave-uniform branch)
  if (kh == 0) {
    #pragma unroll
    for (int d = 0; d < 8; ++d) As[d][t] = acc[d];
  }
  __syncthreads();
  if (kh == 1) {
    #pragma unroll
    for (int d = 0; d < 8; ++d) As[d][t] += acc[d];
  }
  __syncthreads();

  // ---- softmax: wave wu owns d-row wu (8 waves = 8 rows)
  {
    float4 x = *(const float4*)&As[wu][lane * 4];
    float m = fminf(fminf(x.x, x.y), fminf(x.z, x.w));
    #pragma unroll
    for (int off = 32; off; off >>= 1) m = fminf(m, __shfl_xor(m, off));
    float p0 = __builtin_amdgcn_exp2f(C2LOG2E * (m - x.x));
    float p1 = __builtin_amdgcn_exp2f(C2LOG2E * (m - x.y));
    float p2 = __builtin_amdgcn_exp2f(C2LOG2E * (m - x.z));
    float p3 = __builtin_amdgcn_exp2f(C2LOG2E * (m - x.w));
    float s = (p0 + p1) + (p2 + p3);
    #pragma unroll
    for (int off = 32; off; off >>= 1) s += __shfl_xor(s, off);
    float r = __builtin_amdgcn_rcpf(s);
    float4 ev = {p0 * r, p1 * r, p2 * r, p3 * r};
    *(float4*)(e_out + ((size_t)(b * TDD) + d0 + wu) * TEE + lane * 4) = ev;
    *(ushort2*)&pe[wu][lane * 4]     = make_ushort2(f2bf(ev.x), f2bf(ev.y));
    *(ushort2*)&pe[wu][lane * 4 + 2] = make_ushort2(f2bf(ev.z), f2bf(ev.w));
  }
  __syncthreads();

  // ---- ctx: wave wu covers h = wu*64 .. +64 (4 col-tiles); A rows 8..15 zero
  const int r15 = lane & 15, g = lane >> 4;
  const int hw = wu * 64;
  floatx4 ca[4] = {{0.f,0.f,0.f,0.f},{0.f,0.f,0.f,0.f},
                   {0.f,0.f,0.f,0.f},{0.f,0.f,0.f,0.f}};
  const unsigned short* bp0 = encT + ((size_t)b * HH + hw + r15) * TEE + g * 8;

  for (int k0 = 0; k0 < TEE; k0 += 32) {
    short8 a = {0,0,0,0,0,0,0,0};
    if (r15 < 8) a = *(const short8*)&pe[r15][k0 + g * 8];
    #pragma unroll
    for (int nt = 0; nt < 4; ++nt) {
      short8 bv = *(const short8*)(bp0 + (size_t)nt * 16 * TEE + k0);
      ca[nt] = __builtin_amdgcn_mfma_f32_16x16x32_bf16(a, bv, ca[nt], 0, 0, 0);
    }
  }
  // D rows g*4+r: valid d-rows 0..7 -> only g<2 stores
  if (g < 2) {
    #pragma unroll
    for (int nt = 0; nt < 4; ++nt) {
      float* cp = c_out + ((size_t)(b * TDD) + d0 + g * 4) * HH + hw + nt * 16 + r15;
      #pragma unroll
      for (int r = 0; r < 4; ++r) cp[(size_t)r * HH] = ca[nt][r];
    }
  }
}

extern "C" void kernel_launch(void* const* d_in, const int* in_sizes, int n_in,
                              void* d_out, int out_size, void* d_ws, size_t ws_size,
                              hipStream_t stream) {
  const float* enc = (const float*)d_in[0];
  const float* dec = (const float*)d_in[1];
  const float* Wa  = (const float*)d_in[2];
  const float* Ua  = (const float*)d_in[3];
  const float* Va  = (const float*)d_in[4];

  float* c_out = (float*)d_out;                          // f32 c [B*TD*H]
  float* e_out = c_out + (size_t)BB * TDD * HH;          // f32 e [B*TD*TE]

  float* EW4 = (float*)d_ws;                             // f32 4MB (transposed layout)
  float* EU  = EW4 + (size_t)BB * TEE * HH;              // f32 4MB
  unsigned short* encT = (unsigned short*)(EU + (size_t)BB * TDD * HH);  // bf16 2MB

  prep_proj<<<768, 256, 0, stream>>>(enc, dec, Wa, Ua, EW4, EU, encT);
  fused    <<<256, 512, 0, stream>>>(EW4, EU, Va, encT, c_out, e_out);
}

// Round 17
// 66.541 us; speedup vs baseline: 1.5480x; 1.5480x over previous
//
#include <hip/hip_runtime.h>
#include <hip/hip_bf16.h>

// Bahdanau additive attention, MI355X.  B=8, TE=TD=256, HE=HD=512.
// d_in (f32): enc [B,TE,H], dec [B,TD,H], W_a [H,H], U_a [H,H], V_a [H,1]
// d_out (f32): c [B,TD,H] | e [B,TD,TE]
//
// Math: tanh(x) = 1 - 2/(1+e^{2x}).  score = Sv - 2*A,
// A[d,t] = sum_k Va[k]/(1 + EW[t,k]*EU[d,k]),  EW = exp2(clamp(2log2e*enc@Wa,±15)).
// Sv const over t -> dropped; softmax over min(A), -2 folded into exp2 const.
// R17: fused K2 rebalanced. R12 PMC: VALU 14us vs LDS 20.5us both at ~45% duty
//   (per-kg chain 112cy < ew L2 latency; depth-2 prefetch blew VGPR in R14).
//   Now thread = (2 t, 8 d), k quartered per wave-pair: per-kg chain 448cy
//   (depth-1 prefetch suffices) and LDS/elem halves (8 ds serve 64 elems).
//   Partials -> As4[kq], one barrier, softmax sums 4 slabs. R16 scalar-pipe
//   reverted (s_load serialization: 85us).
// ws (10MB): EW4 4M | EU 4M | encT 2M

#define BB  8
#define TEE 256
#define TDD 256
#define HH  512
#define C2LOG2E 2.8853900817779268f   // 2*log2(e)

typedef __attribute__((ext_vector_type(8))) short  short8;
typedef __attribute__((ext_vector_type(4))) float  floatx4;

__device__ __forceinline__ unsigned short f2bf(float f) {
  __hip_bfloat16 h = __float2bfloat16(f);      // RNE
  return __builtin_bit_cast(unsigned short, h);
}

// ---------------- K1: proj -> EW4 (transposed) / EU (row-major) + encT ----------------
// grid 768 x 256thr: blocks 0..255 EW4, 256..511 EU, 512..767 encT.
__global__ __launch_bounds__(256) void prep_proj(
    const float* __restrict__ enc, const float* __restrict__ dec,
    const float* __restrict__ Wa,  const float* __restrict__ Ua,
    float* __restrict__ EW4, float* __restrict__ EU,
    unsigned short* __restrict__ encT)
{
  __shared__ float tile[64][68];
  const int bid = blockIdx.x;
  const int tid = threadIdx.x;

  if (bid < 512) {
    const int side = bid >> 8;               // 0 = EW, 1 = EU
    const int lb = bid & 255;
    const float* X = side ? dec : enc;
    const float* W = side ? Ua  : Wa;
    const int lane = tid & 63, w = tid >> 6;
    const int m0b = (lb >> 3) * 64;          // block m-base (64 rows)
    const int m0 = m0b + w * 16;             // wave's 16 rows
    const int n0 = (lb & 7) * 64;
    const int r15 = lane & 15, g = lane >> 4;

    floatx4 acc[4] = {{0.f,0.f,0.f,0.f},{0.f,0.f,0.f,0.f},
                      {0.f,0.f,0.f,0.f},{0.f,0.f,0.f,0.f}};
    const float* ap = X + (size_t)(m0 + r15) * HH + g * 8;

    for (int k0 = 0; k0 < HH; k0 += 32) {
      float4 a0 = *(const float4*)(ap + k0);
      float4 a1 = *(const float4*)(ap + k0 + 4);
      short8 a;                               // 2log2e folded into A side
      a[0]=(short)f2bf(a0.x*C2LOG2E); a[1]=(short)f2bf(a0.y*C2LOG2E);
      a[2]=(short)f2bf(a0.z*C2LOG2E); a[3]=(short)f2bf(a0.w*C2LOG2E);
      a[4]=(short)f2bf(a1.x*C2LOG2E); a[5]=(short)f2bf(a1.y*C2LOG2E);
      a[6]=(short)f2bf(a1.z*C2LOG2E); a[7]=(short)f2bf(a1.w*C2LOG2E);
      const float* wrow = W + (size_t)(k0 + g * 8) * HH + n0 + r15;
      #pragma unroll
      for (int nt = 0; nt < 4; ++nt) {
        short8 bv;
        #pragma unroll
        for (int j = 0; j < 8; ++j) bv[j] = (short)f2bf(wrow[(size_t)j * HH + nt * 16]);
        acc[nt] = __builtin_amdgcn_mfma_f32_16x16x32_bf16(a, bv, acc[nt], 0, 0, 0);
      }
    }
    // D: col = lane&15, row = (lane>>4)*4 + reg  [m89-verified]
    if (side == 1) {
      // EU: direct row-major [d][k] write
      #pragma unroll
      for (int nt = 0; nt < 4; ++nt) {
        float* yp = EU + (size_t)(m0 + g * 4) * HH + n0 + nt * 16 + r15;
        #pragma unroll
        for (int r = 0; r < 4; ++r) {
          float v = fminf(fmaxf(acc[nt][r], -15.f), 15.f);
          yp[(size_t)r * HH] = __builtin_amdgcn_exp2f(v);
        }
      }
    } else {
      // EW: exp2 -> LDS tile -> transposed coalesced write to EW4
      #pragma unroll
      for (int nt = 0; nt < 4; ++nt) {
        #pragma unroll
        for (int r = 0; r < 4; ++r) {
          float v = fminf(fmaxf(acc[nt][r], -15.f), 15.f);
          tile[w * 16 + g * 4 + r][nt * 16 + r15] = __builtin_amdgcn_exp2f(v);
        }
      }
      __syncthreads();
      // EW4 elem (k,t): b*131072 + (k>>2)*1024 + t*4 + (k&3)
      #pragma unroll
      for (int i = 0; i < 4; ++i) {
        const int cell = i * 256 + tid;        // 1024 cells = 64 t x 16 k4
        const int tl  = cell & 63;
        const int k4l = cell >> 6;
        const int m   = m0b + tl;
        const int b   = m >> 8, t = m & 255;
        const int k4  = (n0 >> 2) + k4l;
        float4 val = *(const float4*)&tile[tl][k4l * 4];
        *(float4*)(EW4 + (size_t)b * 131072 + (size_t)k4 * 1024 + t * 4) = val;
      }
    }
  } else {
    // encT[b][h][t] = bf16(enc[b][t][h]); 256 blocks: 8 b x 8 h-tiles x 4 t-tiles
    const int idx = bid - 512;
    const int b  = idx >> 5;
    const int h0 = ((idx >> 2) & 7) * 64;
    const int t0 = (idx & 3) * 64;
    const int c = tid & 63, r4 = tid >> 6;
    #pragma unroll
    for (int i = 0; i < 16; ++i) {
      int tr = i * 4 + r4;
      tile[tr][c] = enc[((size_t)b * TEE + t0 + tr) * HH + h0 + c];
    }
    __syncthreads();
    #pragma unroll
    for (int i = 0; i < 16; ++i) {
      int hr = i * 4 + r4;
      encT[((size_t)b * HH + h0 + hr) * TEE + t0 + c] = f2bf(tile[c][hr]);
    }
  }
}

// ---------------- K2: score (2t x 8d per thread, kq split) + softmax + ctx ----------------
// grid 256 = 8 b x 32 d-stripes of 8; block 512 thr = 8 waves.
// kq = tid>>7 (wave-pair k-quarter, 128 k), tl = tid&127; thread covers t = tl, tl+128.
__global__ __launch_bounds__(512, 2) void fused(
    const float* __restrict__ EW4, const float* __restrict__ EU,
    const float* __restrict__ Va, const unsigned short* __restrict__ encT,
    float* __restrict__ c_out, float* __restrict__ e_out)
{
  __shared__ float euL[8][512];            // 16 KB
  __shared__ float As4[4][8][260];         // 33.3 KB (per-kq partials)
  __shared__ unsigned short pe[8][264];    // 4.2 KB

  const int bid = blockIdx.x;
  const int b  = bid >> 5;
  const int d0 = (bid & 31) * 8;
  const int tid = threadIdx.x;
  const int lane = tid & 63;
  const int kq = tid >> 7;                 // 0..3, wave-uniform
  const int tl = tid & 127;                // covers t = tl and tl + 128

  // stage EU rows d0..d0+7 (coalesced)
  {
    const int dr = tid >> 6, kk = lane * 8;
    const float* src = EU + ((size_t)(b * TDD) + d0 + dr) * HH + kk;
    *(float4*)&euL[dr][kk]     = *(const float4*)(src);
    *(float4*)&euL[dr][kk + 4] = *(const float4*)(src + 4);
  }
  __syncthreads();

#define TREE(EW_, U_, V_, AC_) { \
    float A1 = fmaf(EW_.x, U_.x, 1.0f); \
    float B1 = fmaf(EW_.y, U_.y, 1.0f); \
    float C1 = fmaf(EW_.z, U_.z, 1.0f); \
    float D1 = fmaf(EW_.w, U_.w, 1.0f); \
    float dab = A1 * B1, dcd = C1 * D1; \
    float nab = fmaf(V_.x, B1, V_.y * A1); \
    float ncd = fmaf(V_.z, D1, V_.w * C1); \
    AC_ = fmaf(fmaf(nab, dcd, ncd * dab), \
               __builtin_amdgcn_rcpf(dab * dcd), AC_); }

  // ---- score: 4-way rcp tree; per kg: 2 ew float4 (global) + 8 u (LDS bcast)
  float acc[8][2] = {};                    // [d][tpair]
  // EW4 elem (k,t): b*131072 + (k>>2)*1024 + t*4 + (k&3); k = kq*128 + kg*4 + j
  const float* ewp = EW4 + (size_t)b * 131072 + (size_t)(kq * 32) * 1024 + tl * 4;
  const float* vap = Va + kq * 128;
  const int kb = kq * 128;

  float4 ew0 = *(const float4*)(ewp);            // t = tl
  float4 ew1 = *(const float4*)(ewp + 512);      // t = tl + 128

  for (int kg = 0; kg < 32; ++kg) {
    float4 n0, n1;
    if (kg + 1 < 32) {                     // depth-1 prefetch; 448cy chain covers L2
      n0 = *(const float4*)(ewp + (size_t)(kg + 1) * 1024);
      n1 = *(const float4*)(ewp + (size_t)(kg + 1) * 1024 + 512);
    }
    float4 v = *(const float4*)(vap + kg * 4);   // uniform, L1-resident
    #pragma unroll
    for (int d = 0; d < 8; ++d) {
      float4 u = *(const float4*)&euL[d][kb + kg * 4];   // broadcast
      TREE(ew0, u, v, acc[d][0])
      TREE(ew1, u, v, acc[d][1])
    }
    ew0 = n0; ew1 = n1;
  }
#undef TREE

  // per-kq partials (disjoint slabs, no cross-wave hazard)
  #pragma unroll
  for (int d = 0; d < 8; ++d) {
    As4[kq][d][tl]       = acc[d][0];
    As4[kq][d][tl + 128] = acc[d][1];
  }
  __syncthreads();

  // ---- softmax: wave wu owns d-row wu; sum the 4 kq slabs
  const int wu = tid >> 6;
  {
    float4 x = {0.f, 0.f, 0.f, 0.f};
    #pragma unroll
    for (int s2 = 0; s2 < 4; ++s2) {
      float4 xs = *(const float4*)&As4[s2][wu][lane * 4];
      x.x += xs.x; x.y += xs.y; x.z += xs.z; x.w += xs.w;
    }
    float m = fminf(fminf(x.x, x.y), fminf(x.z, x.w));
    #pragma unroll
    for (int off = 32; off; off >>= 1) m = fminf(m, __shfl_xor(m, off));
    float p0 = __builtin_amdgcn_exp2f(C2LOG2E * (m - x.x));
    float p1 = __builtin_amdgcn_exp2f(C2LOG2E * (m - x.y));
    float p2 = __builtin_amdgcn_exp2f(C2LOG2E * (m - x.z));
    float p3 = __builtin_amdgcn_exp2f(C2LOG2E * (m - x.w));
    float s = (p0 + p1) + (p2 + p3);
    #pragma unroll
    for (int off = 32; off; off >>= 1) s += __shfl_xor(s, off);
    float r = __builtin_amdgcn_rcpf(s);
    float4 ev = {p0 * r, p1 * r, p2 * r, p3 * r};
    *(float4*)(e_out + ((size_t)(b * TDD) + d0 + wu) * TEE + lane * 4) = ev;
    *(ushort2*)&pe[wu][lane * 4]     = make_ushort2(f2bf(ev.x), f2bf(ev.y));
    *(ushort2*)&pe[wu][lane * 4 + 2] = make_ushort2(f2bf(ev.z), f2bf(ev.w));
  }
  __syncthreads();

  // ---- ctx: wave wu covers h = wu*64 .. +64 (4 col-tiles); A rows 8..15 zero
  const int r15 = lane & 15, g = lane >> 4;
  const int hw = wu * 64;
  floatx4 ca[4] = {{0.f,0.f,0.f,0.f},{0.f,0.f,0.f,0.f},
                   {0.f,0.f,0.f,0.f},{0.f,0.f,0.f,0.f}};
  const unsigned short* bp0 = encT + ((size_t)b * HH + hw + r15) * TEE + g * 8;

  for (int k0 = 0; k0 < TEE; k0 += 32) {
    short8 a = {0,0,0,0,0,0,0,0};
    if (r15 < 8) a = *(const short8*)&pe[r15][k0 + g * 8];
    #pragma unroll
    for (int nt = 0; nt < 4; ++nt) {
      short8 bv = *(const short8*)(bp0 + (size_t)nt * 16 * TEE + k0);
      ca[nt] = __builtin_amdgcn_mfma_f32_16x16x32_bf16(a, bv, ca[nt], 0, 0, 0);
    }
  }
  // D rows g*4+r: valid d-rows 0..7 -> only g<2 stores
  if (g < 2) {
    #pragma unroll
    for (int nt = 0; nt < 4; ++nt) {
      float* cp = c_out + ((size_t)(b * TDD) + d0 + g * 4) * HH + hw + nt * 16 + r15;
      #pragma unroll
      for (int r = 0; r < 4; ++r) cp[(size_t)r * HH] = ca[nt][r];
    }
  }
}

extern "C" void kernel_launch(void* const* d_in, const int* in_sizes, int n_in,
                              void* d_out, int out_size, void* d_ws, size_t ws_size,
                              hipStream_t stream) {
  const float* enc = (const float*)d_in[0];
  const float* dec = (const float*)d_in[1];
  const float* Wa  = (const float*)d_in[2];
  const float* Ua  = (const float*)d_in[3];
  const float* Va  = (const float*)d_in[4];

  float* c_out = (float*)d_out;                          // f32 c [B*TD*H]
  float* e_out = c_out + (size_t)BB * TDD * HH;          // f32 e [B*TD*TE]

  float* EW4 = (float*)d_ws;                             // f32 4MB (transposed layout)
  float* EU  = EW4 + (size_t)BB * TEE * HH;              // f32 4MB
  unsigned short* encT = (unsigned short*)(EU + (size_t)BB * TDD * HH);  // bf16 2MB

  prep_proj<<<768, 256, 0, stream>>>(enc, dec, Wa, Ua, EW4, EU, encT);
  fused    <<<256, 512, 0, stream>>>(EW4, EU, Va, encT, c_out, e_out);
}

// Round 18
// 60.957 us; speedup vs baseline: 1.6898x; 1.0916x over previous
//
#include <hip/hip_runtime.h>
#include <hip/hip_bf16.h>

// Bahdanau additive attention, MI355X.  B=8, TE=TD=256, HE=HD=512.
// d_in (f32): enc [B,TE,H], dec [B,TD,H], W_a [H,H], U_a [H,H], V_a [H,1]
// d_out (f32): c [B,TD,H] | e [B,TD,TE]
//
// Math: tanh(x) = 1 - 2/(1+e^{2x}).  score = Sv - 2*A,
// A[d,t] = sum_k Va[k]/(1 + EW[t,k]*EU[d,k]),  EW = exp2(clamp(2log2e*enc@Wa,±15)).
// Sv const over t -> dropped; softmax over min(A), -2 folded into exp2 const.
//
// R18 = R10 verbatim (best measured: 60.9us). The 2-kernel fused variants
// (R12-R17: 63.9-85.5) all lose to this 3-kernel pipeline: the fused score
// kernel pins at ~48us / 39-48% VALU duty across every occupancy, prefetch,
// scalar-pipe and LDS configuration tested. 4-way rcp tree (1 v_rcp / 4 k,
// clamp +-15 keeps den finite) + native cvt_pk bf16 + k-split-8 score.
// ws (~26MB): encT 2M | EW 4M | EU 4M | Apart 8x2M

#define BB  8
#define TEE 256
#define TDD 256
#define HH  512
#define C2LOG2E 2.8853900817779268f   // 2*log2(e)
#define SLAB ((size_t)BB * TDD * TEE)
#define NKS 8                          // k-split slices

typedef __attribute__((ext_vector_type(8))) short  short8;
typedef __attribute__((ext_vector_type(4))) float  floatx4;

__device__ __forceinline__ unsigned short f2bf(float f) {
  __hip_bfloat16 h = __float2bfloat16(f);      // RNE; compiler packs into cvt_pk
  return __builtin_bit_cast(unsigned short, h);
}

// ---------- kernel 1: proj (EW, EU) + encT transpose, one launch ----------
// blocks 0..255: EW; 256..511: EU; 512..767: encT.  block 256 thr = 4 waves.
__global__ __launch_bounds__(256) void proj_all(
    const float* __restrict__ enc, const float* __restrict__ dec,
    const float* __restrict__ Wa,  const float* __restrict__ Ua,
    float* __restrict__ EW, float* __restrict__ EU,
    unsigned short* __restrict__ encT)
{
  __shared__ float tile[64][65];
  const int bid = blockIdx.x;

  if (bid < 512) {
    const int side = bid >> 8;               // 0 = EW, 1 = EU
    const int lb = bid & 255;
    const float* X = side ? dec : enc;
    const float* W = side ? Ua  : Wa;
    float*       Y = side ? EU  : EW;
    const int lane = threadIdx.x & 63, w = threadIdx.x >> 6;
    const int m0 = (lb >> 3) * 64 + w * 16;  // 32 m-tiles of 64, wave picks 16
    const int n0 = (lb & 7) * 64;
    const int r15 = lane & 15, g = lane >> 4;

    floatx4 acc[4] = {{0.f,0.f,0.f,0.f},{0.f,0.f,0.f,0.f},
                      {0.f,0.f,0.f,0.f},{0.f,0.f,0.f,0.f}};
    const float* ap = X + (size_t)(m0 + r15) * HH + g * 8;

    for (int k0 = 0; k0 < HH; k0 += 32) {
      float4 a0 = *(const float4*)(ap + k0);
      float4 a1 = *(const float4*)(ap + k0 + 4);
      short8 a;                                 // scale folded into A side
      a[0]=(short)f2bf(a0.x*C2LOG2E); a[1]=(short)f2bf(a0.y*C2LOG2E);
      a[2]=(short)f2bf(a0.z*C2LOG2E); a[3]=(short)f2bf(a0.w*C2LOG2E);
      a[4]=(short)f2bf(a1.x*C2LOG2E); a[5]=(short)f2bf(a1.y*C2LOG2E);
      a[6]=(short)f2bf(a1.z*C2LOG2E); a[7]=(short)f2bf(a1.w*C2LOG2E);
      const float* wrow = W + (size_t)(k0 + g * 8) * HH + n0 + r15;
      #pragma unroll
      for (int nt = 0; nt < 4; ++nt) {
        short8 bv;                              // strided W reads, native cvt
        #pragma unroll
        for (int j = 0; j < 8; ++j) bv[j] = (short)f2bf(wrow[(size_t)j * HH + nt * 16]);
        acc[nt] = __builtin_amdgcn_mfma_f32_16x16x32_bf16(a, bv, acc[nt], 0, 0, 0);
      }
    }
    // D: col = lane&15, row = (lane>>4)*4 + reg  [m89-verified]
    #pragma unroll
    for (int nt = 0; nt < 4; ++nt) {
      float* yp = Y + (size_t)(m0 + g * 4) * HH + n0 + nt * 16 + r15;
      #pragma unroll
      for (int r = 0; r < 4; ++r) {
        float v = fminf(fmaxf(acc[nt][r], -15.f), 15.f);  // den4 stays finite
        yp[(size_t)r * HH] = __builtin_amdgcn_exp2f(v);
      }
    }
  } else {
    // encT[b][h][t] = bf16(enc[b][t][h]);  256 blocks: 8 b x 8 h-tiles x 4 t-tiles
    const int idx = bid - 512;
    const int b  = idx >> 5;
    const int h0 = ((idx >> 2) & 7) * 64;
    const int t0 = (idx & 3) * 64;
    const int c = threadIdx.x & 63, r4 = threadIdx.x >> 6;
    #pragma unroll
    for (int i = 0; i < 16; ++i) {
      int tr = i * 4 + r4;
      tile[tr][c] = enc[((size_t)b * TEE + t0 + tr) * HH + h0 + c];
    }
    __syncthreads();
    #pragma unroll
    for (int i = 0; i < 16; ++i) {
      int hr = i * 4 + r4;
      encT[((size_t)b * HH + h0 + hr) * TEE + t0 + c] = f2bf(tile[c][hr]);
    }
  }
}

// ---------- kernel 2: Apart[ks][b,d,t] = sum_{k slice of 64} Va[k]/(1+EW*EU) ----------
// 64t x 64d tile, 4x4/thread, k-split 8, dbuf LDS, 4-WAY rcp tree (1 rcp / 4 k).
// grid (32 = 4 t-tiles x 8 ks, 4 d-tiles, 8 b), block 256 -> 1024 blocks.
__global__ __launch_bounds__(256) void score_rt(
    const float* __restrict__ EW, const float* __restrict__ EU,
    const float* __restrict__ Va, float* __restrict__ Apart)
{
  __shared__ float swT[2][32][68];   // [buf][k][t]
  __shared__ float suT[2][32][68];   // [buf][k][d]

  const int b  = blockIdx.z;
  const int ks = blockIdx.x >> 2;            // k-slice 0..7 (64 k each)
  const int t0 = (blockIdx.x & 3) * 64;
  const int d0 = blockIdx.y * 64;
  const int kbase = ks * 64;
  const int tid = threadIdx.x;
  const int tx = tid & 15, ty = tid >> 4;    // thread -> 4t x 4d
  const int sr = tid >> 2, fq = tid & 3;     // staging: row 0..63, quad 0..3
  const int kq = fq * 4;

  const float* wsrc = EW + ((size_t)(b * TEE) + t0 + sr) * HH + kbase + kq;
  const float* usrc = EU + ((size_t)(b * TDD) + d0 + sr) * HH + kbase + kq;

  float acc[4][4] = {};   // [d j][t i]

#define STAGE(BUF_, W0_, W1_, U0_, U1_) {                         \
    swT[BUF_][kq + 0][sr] = W0_.x; swT[BUF_][kq + 1][sr] = W0_.y; \
    swT[BUF_][kq + 2][sr] = W0_.z; swT[BUF_][kq + 3][sr] = W0_.w; \
    swT[BUF_][kq +16][sr] = W1_.x; swT[BUF_][kq +17][sr] = W1_.y; \
    swT[BUF_][kq +18][sr] = W1_.z; swT[BUF_][kq +19][sr] = W1_.w; \
    suT[BUF_][kq + 0][sr] = U0_.x; suT[BUF_][kq + 1][sr] = U0_.y; \
    suT[BUF_][kq + 2][sr] = U0_.z; suT[BUF_][kq + 3][sr] = U0_.w; \
    suT[BUF_][kq +16][sr] = U1_.x; suT[BUF_][kq +17][sr] = U1_.y; \
    suT[BUF_][kq +18][sr] = U1_.z; suT[BUF_][kq +19][sr] = U1_.w; }

  {   // prologue: chunk 0 -> buf 0
    float4 w0 = *(const float4*)(wsrc);
    float4 w1 = *(const float4*)(wsrc + 16);
    float4 u0 = *(const float4*)(usrc);
    float4 u1 = *(const float4*)(usrc + 16);
    STAGE(0, w0, w1, u0, u1)
  }

  for (int ch = 0; ch < 2; ++ch) {           // 2 chunks of 32 k
    float4 nw0, nw1, nu0, nu1;
    const bool more = (ch == 0);
    if (more) {                              // prefetch next chunk into regs
      nw0 = *(const float4*)(wsrc + 32);
      nw1 = *(const float4*)(wsrc + 48);
      nu0 = *(const float4*)(usrc + 32);
      nu1 = *(const float4*)(usrc + 48);
    }
    __syncthreads();                         // buf[ch] writes visible

    const float* vb = Va + kbase + ch * 32;

    // 4-way tree: leaves (num=v_i, den=1+a_i); combine (n,d),(n',d') ->
    //   den = d*d', num = n*d' + n'*d;  one rcp per 4 k.
    #pragma unroll 2
    for (int kk = 0; kk < 32; kk += 4) {
      floatx4 wA = *(const floatx4*)&swT[ch][kk    ][tx * 4];
      floatx4 wB = *(const floatx4*)&swT[ch][kk + 1][tx * 4];
      floatx4 wC = *(const floatx4*)&swT[ch][kk + 2][tx * 4];
      floatx4 wD = *(const floatx4*)&swT[ch][kk + 3][tx * 4];
      floatx4 uA = *(const floatx4*)&suT[ch][kk    ][ty * 4];
      floatx4 uB = *(const floatx4*)&suT[ch][kk + 1][ty * 4];
      floatx4 uC = *(const floatx4*)&suT[ch][kk + 2][ty * 4];
      floatx4 uD = *(const floatx4*)&suT[ch][kk + 3][ty * 4];
      float4 vv = *(const float4*)(vb + kk);   // uniform -> s_load
      #pragma unroll
      for (int j = 0; j < 4; ++j) {
        float u1 = uA[j], u2 = uB[j], u3 = uC[j], u4 = uD[j];
        #pragma unroll
        for (int i = 0; i < 4; ++i) {
          float A1 = fmaf(wA[i], u1, 1.0f);
          float B1 = fmaf(wB[i], u2, 1.0f);
          float C1 = fmaf(wC[i], u3, 1.0f);
          float D1 = fmaf(wD[i], u4, 1.0f);
          float dab = A1 * B1;
          float nab = fmaf(vv.x, B1, vv.y * A1);
          float dcd = C1 * D1;
          float ncd = fmaf(vv.z, D1, vv.w * C1);
          float den = dab * dcd;
          float num = fmaf(nab, dcd, ncd * dab);
          acc[j][i] = fmaf(num, __builtin_amdgcn_rcpf(den), acc[j][i]);
        }
      }
    }

    if (more) STAGE(1, nw0, nw1, nu0, nu1)   // other buf: no hazard
  }
#undef STAGE

  float* Ap = Apart + (size_t)ks * SLAB;
  #pragma unroll
  for (int j = 0; j < 4; ++j) {
    const int d = d0 + ty * 4 + j;
    floatx4 o = {acc[j][0], acc[j][1], acc[j][2], acc[j][3]};
    *(floatx4*)(Ap + ((size_t)(b * TDD) + d) * TEE + t0 + tx * 4) = o;
  }
}

// ---------- kernel 3: softmax(sum Apart) -> e; c = e @ enc (bf16 MFMA) ----------
// grid (16 d-tiles of 16, 4 h-quarters of 128, 8 b) = 512 blocks, block 256 = 4 waves.
__global__ __launch_bounds__(256) void ctx_fused(
    const float* __restrict__ Apart, const unsigned short* __restrict__ encT,
    float* __restrict__ c, float* __restrict__ e_out)
{
  __shared__ unsigned short pe[16][264];

  const int b  = blockIdx.z;
  const int d0 = blockIdx.x * 16;
  const int h0 = blockIdx.y * 128;
  const int lane = threadIdx.x & 63, w = threadIdx.x >> 6;

  // --- softmax: wave w owns rows w*4 + (lane>>4); 16 lanes/row, 16 cols/lane
  {
    const int row  = w * 4 + (lane >> 4);
    const int col0 = (lane & 15) * 16;
    const size_t base = ((size_t)(b * TDD) + d0 + row) * TEE + col0;
    float x[16];
    #pragma unroll
    for (int q = 0; q < 4; ++q) {
      floatx4 v = *(const floatx4*)(Apart + base + q * 4);
      x[4*q] = v[0]; x[4*q+1] = v[1]; x[4*q+2] = v[2]; x[4*q+3] = v[3];
    }
    #pragma unroll
    for (int s = 1; s < NKS; ++s) {
      #pragma unroll
      for (int q = 0; q < 4; ++q) {
        floatx4 v = *(const floatx4*)(Apart + (size_t)s * SLAB + base + q * 4);
        x[4*q] += v[0]; x[4*q+1] += v[1]; x[4*q+2] += v[2]; x[4*q+3] += v[3];
      }
    }
    float m = x[0];
    #pragma unroll
    for (int j = 1; j < 16; ++j) m = fminf(m, x[j]);
    #pragma unroll
    for (int off = 8; off; off >>= 1) m = fminf(m, __shfl_xor(m, off)); // 16-lane grp
    float p[16], s = 0.f;
    #pragma unroll
    for (int j = 0; j < 16; ++j) {
      p[j] = __builtin_amdgcn_exp2f(C2LOG2E * (m - x[j]));
      s += p[j];
    }
    #pragma unroll
    for (int off = 8; off; off >>= 1) s += __shfl_xor(s, off);
    float r = __builtin_amdgcn_rcpf(s);

    #pragma unroll
    for (int j = 0; j < 16; j += 2) {
      float v0 = p[j] * r, v1 = p[j+1] * r;
      *(ushort2*)&pe[row][col0 + j] = make_ushort2(f2bf(v0), f2bf(v1));
    }
    if (blockIdx.y == 0) {
      float* er = e_out + ((size_t)(b * TDD) + d0 + row) * TEE + col0;
      #pragma unroll
      for (int j = 0; j < 16; ++j) er[j] = p[j] * r;
    }
  }
  __syncthreads();

  // --- MFMA: wave w covers h = h0 + w*32 .. +32 (2 col-tiles)
  const int r15 = lane & 15, g = lane >> 4;
  const int hw = h0 + w * 32;
  floatx4 acc0 = {0.f,0.f,0.f,0.f}, acc1 = {0.f,0.f,0.f,0.f};
  const unsigned short* bp0 = encT + ((size_t)b * HH + hw + r15) * TEE + g * 8;

  for (int k0 = 0; k0 < TEE; k0 += 32) {
    short8 a = *(const short8*)(&pe[r15][k0 + g * 8]);
    short8 bv0 = *(const short8*)(bp0 + k0);
    short8 bv1 = *(const short8*)(bp0 + (size_t)16 * TEE + k0);
    acc0 = __builtin_amdgcn_mfma_f32_16x16x32_bf16(a, bv0, acc0, 0, 0, 0);
    acc1 = __builtin_amdgcn_mfma_f32_16x16x32_bf16(a, bv1, acc1, 0, 0, 0);
  }
  floatx4 aall[2] = {acc0, acc1};
  #pragma unroll
  for (int nt = 0; nt < 2; ++nt) {
    float* cp = c + ((size_t)(b * TDD) + d0 + g * 4) * HH + hw + nt * 16 + r15;
    #pragma unroll
    for (int r = 0; r < 4; ++r) cp[(size_t)r * HH] = aall[nt][r];
  }
}

extern "C" void kernel_launch(void* const* d_in, const int* in_sizes, int n_in,
                              void* d_out, int out_size, void* d_ws, size_t ws_size,
                              hipStream_t stream) {
  const float* enc = (const float*)d_in[0];
  const float* dec = (const float*)d_in[1];
  const float* Wa  = (const float*)d_in[2];
  const float* Ua  = (const float*)d_in[3];
  const float* Va  = (const float*)d_in[4];

  float* c_out = (float*)d_out;                          // f32 c [B*TD*H]
  float* e_out = c_out + (size_t)BB * TDD * HH;          // f32 e [B*TD*TE]

  unsigned short* encT = (unsigned short*)d_ws;          // bf16 2MB
  float* EW    = (float*)(encT + (size_t)BB * HH * TEE); // f32 4MB
  float* EU    = EW + (size_t)BB * TEE * HH;             // f32 4MB
  float* Apart = EU + (size_t)BB * TDD * HH;             // f32 8 x 2MB

  proj_all  <<<768,              256, 0, stream>>>(enc, dec, Wa, Ua, EW, EU, encT);
  score_rt  <<<dim3(32, 4, 8),   256, 0, stream>>>(EW, EU, Va, Apart);
  ctx_fused <<<dim3(16, 4, 8),   256, 0, stream>>>(Apart, encT, c_out, e_out);
}